// Round 1
// baseline (2864.660 us; speedup 1.0000x reference)
//
#include <hip/hip_runtime.h>
#include <math.h>

typedef short  bf16x8 __attribute__((ext_vector_type(8)));
typedef float  f32x4  __attribute__((ext_vector_type(4)));

__device__ __forceinline__ unsigned short bf16_rn(float x) {
    unsigned u = __float_as_uint(x);
    u += 0x7fffu + ((u >> 16) & 1u);
    return (unsigned short)(u >> 16);
}
__device__ __forceinline__ float bf16f(unsigned short h) {
    return __uint_as_float(((unsigned)h) << 16);
}

// async global->LDS, 16B per lane. HW writes LDS at wave-uniform base + lane*16
// (m104/m108); per-lane GLOBAL address carries the layout permutation (m173).
__device__ __forceinline__ void gl2lds16(const void* gptr, void* lptr) {
    __builtin_amdgcn_global_load_lds(
        (const __attribute__((address_space(1))) unsigned int*)(unsigned long long)gptr,
        (__attribute__((address_space(3))) unsigned int*)(unsigned int)(unsigned long long)lptr,
        16, 0, 0);
}

// ==================== MFMA split-bf16 GEMM =================================
// C = scale*(A@B) [+ bias], computed as Ah*Bh + Ah*Bl + Al*Bh on bf16 MFMA
// (dropped Al*Bl term ~2^-16 relative -- fp32-grade accuracy).
// A operand: [M][K] rows (hi/lo bf16). B operand: [N][K] rows (hi/lo bf16).
// Tile 128x128, BK=32, 256 threads = 4 waves in 2x2, each wave 4x4 of
// 16x16x32 MFMA. LDS layout per array: [blk 8][kg 4][row 16][8 bf16] (8KB).
// Staging now via global_load_lds_dwordx4: wave wv stages blks {wv, wv+4} of
// each array; lane l supplies global data for (kg=l>>4, row=l&15) so the
// HW's linear lane*16B write reproduces the [kg][row][8] layout exactly.
// OUTM: 0 = fp32 C (o1)    1 = qkv epilogue (o1..o5 = Qh,Ql,Kh,Kl,Vfp32)
//       2 = hi/lo bf16 (o1,o2)
template<int OUTM, bool HAS_BIAS>
__global__ __launch_bounds__(256, 2)
void mgemm(const unsigned short* __restrict__ Ah_, const unsigned short* __restrict__ Al_,
           const unsigned short* __restrict__ Bh_, const unsigned short* __restrict__ Bl_,
           const float* __restrict__ bias,
           void* o1, void* o2, void* o3, void* o4, void* o5,
           int K, int lda, int ldc,
           long long sA, long long sB, long long sC, float scale)
{
    const int tid = threadIdx.x;
    const int bm = blockIdx.y * 128;
    const int bn = blockIdx.x * 128;
    const long long z = blockIdx.z;

    const unsigned short* Ahu = Ah_ + z * sA;
    const unsigned short* Alu = Al_ + z * sA;
    const unsigned short* Bhu = Bh_ + z * sB;
    const unsigned short* Blu = Bl_ + z * sB;

    __shared__ unsigned short LA_h[4096], LA_l[4096], LB_h[4096], LB_l[4096];

    const int wv = tid >> 6, wr = wv >> 1, wc = wv & 1, lane = tid & 63;
    const int fro = (lane >> 4) * 128 + (lane & 15) * 8;  // frag offset in blk

    // per-lane staging source offsets (hoisted out of K-loop)
    const int srow = lane & 15, skg = lane >> 4;
    const size_t gaA0 = (size_t)(bm + 16 * wv       + srow) * lda + skg * 8;
    const size_t gaA1 = (size_t)(bm + 16 * (wv + 4) + srow) * lda + skg * 8;
    const size_t gaB0 = (size_t)(bn + 16 * wv       + srow) * lda + skg * 8;
    const size_t gaB1 = (size_t)(bn + 16 * (wv + 4) + srow) * lda + skg * 8;
    const int lo0 = wv * 512, lo1 = (wv + 4) * 512;   // wave-uniform LDS bases

    f32x4 acc[4][4];
#pragma unroll
    for (int i = 0; i < 4; ++i)
#pragma unroll
        for (int j = 0; j < 4; ++j) acc[i][j] = (f32x4){0.f, 0.f, 0.f, 0.f};

    const int nkt = K >> 5;
    for (int kt = 0; kt < nkt; ++kt) {
        const int k0 = kt << 5;
        __syncthreads();                          // readers of prev tile done
        // ---- stage A+B: 8 x global_load_lds_dwordx4 per wave ----
        gl2lds16(&Ahu[gaA0 + k0], &LA_h[lo0]);
        gl2lds16(&Ahu[gaA1 + k0], &LA_h[lo1]);
        gl2lds16(&Alu[gaA0 + k0], &LA_l[lo0]);
        gl2lds16(&Alu[gaA1 + k0], &LA_l[lo1]);
        gl2lds16(&Bhu[gaB0 + k0], &LB_h[lo0]);
        gl2lds16(&Bhu[gaB1 + k0], &LB_h[lo1]);
        gl2lds16(&Blu[gaB0 + k0], &LB_l[lo0]);
        gl2lds16(&Blu[gaB1 + k0], &LB_l[lo1]);
        __syncthreads();                          // staging visible (vmcnt drain)
        // ---- compute: 48 MFMA per wave per BK=32 ----
        bf16x8 bhf[4], blf[4];
#pragma unroll
        for (int ni = 0; ni < 4; ++ni) {
            int off = (wc * 4 + ni) * 512 + fro;
            bhf[ni] = *(const bf16x8*)&LB_h[off];
            blf[ni] = *(const bf16x8*)&LB_l[off];
        }
#pragma unroll
        for (int mi = 0; mi < 4; ++mi) {
            int off = (wr * 4 + mi) * 512 + fro;
            bf16x8 ah = *(const bf16x8*)&LA_h[off];
            bf16x8 al = *(const bf16x8*)&LA_l[off];
#pragma unroll
            for (int ni = 0; ni < 4; ++ni) {
                f32x4 a = acc[mi][ni];
                a = __builtin_amdgcn_mfma_f32_16x16x32_bf16(ah, bhf[ni], a, 0, 0, 0);
                a = __builtin_amdgcn_mfma_f32_16x16x32_bf16(ah, blf[ni], a, 0, 0, 0);
                a = __builtin_amdgcn_mfma_f32_16x16x32_bf16(al, bhf[ni], a, 0, 0, 0);
                acc[mi][ni] = a;
            }
        }
    }

    // ---- epilogue: C/D layout col=lane&15, row=(lane>>4)*4+r ----
#pragma unroll
    for (int mi = 0; mi < 4; ++mi) {
#pragma unroll
        for (int ni = 0; ni < 4; ++ni) {
            const int grow0 = bm + wr * 64 + mi * 16 + ((lane >> 4) << 2);
            const int gcol  = bn + wc * 64 + ni * 16 + (lane & 15);
            float bb = HAS_BIAS ? bias[gcol] : 0.f;
#pragma unroll
            for (int r = 0; r < 4; ++r) {
                float v = acc[mi][ni][r] * scale + bb;
                const size_t grow = (size_t)(grow0 + r);
                if (OUTM == 0) {
                    ((float*)o1 + z * sC)[grow * ldc + gcol] = v;
                } else if (OUTM == 1) {
                    if (gcol < 768) {
                        unsigned short h = bf16_rn(v);
                        ((unsigned short*)o1)[grow * 768 + gcol] = h;
                        ((unsigned short*)o2)[grow * 768 + gcol] = bf16_rn(v - bf16f(h));
                    } else if (gcol < 1536) {
                        int cc = gcol - 768;
                        unsigned short h = bf16_rn(v);
                        ((unsigned short*)o3)[grow * 768 + cc] = h;
                        ((unsigned short*)o4)[grow * 768 + cc] = bf16_rn(v - bf16f(h));
                    } else {
                        ((float*)o5)[grow * 768 + (gcol - 1536)] = v;
                    }
                } else {
                    unsigned short h = bf16_rn(v);
                    ((unsigned short*)o1 + z * sC)[grow * ldc + gcol] = h;
                    ((unsigned short*)o2 + z * sC)[grow * ldc + gcol] = bf16_rn(v - bf16f(h));
                }
            }
        }
    }
}

// ==================== elementwise fp32 -> hi/lo bf16 split =================
// moves the qkv GEMM's in-K-loop fp32 split out to a one-shot streaming pass
__global__ __launch_bounds__(256)
void split_k(const float* __restrict__ src, unsigned short* __restrict__ dh,
             unsigned short* __restrict__ dl, long long n8)
{
    long long i = (long long)blockIdx.x * 256 + threadIdx.x;
    const long long stride = (long long)gridDim.x * 256;
    for (; i < n8; i += stride) {
        const float4* p = (const float4*)(src + i * 8);
        float4 f0 = p[0], f1 = p[1];
        float ff[8] = {f0.x, f0.y, f0.z, f0.w, f1.x, f1.y, f1.z, f1.w};
        bf16x8 hv, lv;
#pragma unroll
        for (int j = 0; j < 8; ++j) {
            unsigned short h = bf16_rn(ff[j]);
            hv[j] = (short)h;
            lv[j] = (short)bf16_rn(ff[j] - bf16f(h));
        }
        *(bf16x8*)(dh + i * 8) = hv;
        *(bf16x8*)(dl + i * 8) = lv;
    }
}

// ==================== transpose + split to hi/lo bf16 ======================
// src fp32 [R][C] (ld ls) -> dh/dl bf16 [C][R] (ld ld_)
__global__ __launch_bounds__(256)
void tsplit_k(const float* __restrict__ src, unsigned short* __restrict__ dh,
              unsigned short* __restrict__ dl, int ls, long long ss,
              int ld_, long long sd)
{
    src += (long long)blockIdx.z * ss;
    dh  += (long long)blockIdx.z * sd;
    dl  += (long long)blockIdx.z * sd;
    __shared__ float t[32][33];
    const int tx = threadIdx.x & 31, ty = threadIdx.x >> 5;
    const int r0 = blockIdx.y * 32, c0 = blockIdx.x * 32;
#pragma unroll
    for (int i = 0; i < 4; ++i)
        t[ty + 8 * i][tx] = src[(size_t)(r0 + ty + 8 * i) * ls + c0 + tx];
    __syncthreads();
#pragma unroll
    for (int i = 0; i < 4; ++i) {
        float v = t[tx][ty + 8 * i];
        unsigned short h = bf16_rn(v);
        size_t o = (size_t)(c0 + ty + 8 * i) * ld_ + r0 + tx;
        dh[o] = h;
        dl[o] = bf16_rn(v - bf16f(h));
    }
}

// ==================== gw = softmax(V @ w_gp), one wave per row =============
__global__ __launch_bounds__(64)
void gw_k(const float* __restrict__ Vf, const float* __restrict__ wgp,
          float* __restrict__ gw)
{
    const long long row = blockIdx.x;
    const int lane = threadIdx.x;
    const float* v = Vf + row * 768;
    float a0 = 0.f, a1 = 0.f, a2 = 0.f, a3 = 0.f;
    if (lane < 49) {
        for (int d = 0; d < 768; d += 4) {
            float4 vv = *(const float4*)&v[d];
            a0 = fmaf(vv.x, wgp[(d + 0) * 49 + lane], a0);
            a1 = fmaf(vv.y, wgp[(d + 1) * 49 + lane], a1);
            a2 = fmaf(vv.z, wgp[(d + 2) * 49 + lane], a2);
            a3 = fmaf(vv.w, wgp[(d + 3) * 49 + lane], a3);
        }
    }
    float logit = (lane < 49) ? ((a0 + a1) + (a2 + a3)) : -INFINITY;
    float m = logit;
    for (int off = 32; off; off >>= 1) m = fmaxf(m, __shfl_xor(m, off));
    float e = (lane < 49) ? expf(logit - m) : 0.f;
    float s = e;
    for (int off = 32; off; off >>= 1) s += __shfl_xor(s, off);
    if (lane < 49) gw[row * 49 + lane] = e / s;
}

// ==================== fused softmax*G modulation, streaming ================
// attn = w*c/(c*T+eps), w = exp(s-m)*(gw_q.gw_k), c = n/(Z*(SG+eps)).
// 8 q rows/block, 32 threads/row; 3 streaming passes over S (L1/L2-hot)
// keep per-thread state ~20 VGPRs (R3's spill fix). Emits bf16 hi/lo attn.
__global__ __launch_bounds__(256)
void mod_k3(float* __restrict__ S, const float* __restrict__ gw,
            unsigned short* __restrict__ Sh, unsigned short* __restrict__ Sl)
{
    const int qb  = blockIdx.x;           // 0..127
    const int b   = blockIdx.y;           // chunk-local batch
    const int tid = threadIdx.x;
    const int ql  = tid >> 5;             // 0..7
    const int l32 = tid & 31;

    const long long rowg = (long long)b * 1024 + (qb * 8 + ql);
    float* Srow = S + rowg * 1024;
    const float* gwb = gw + (long long)b * 1024 * 49;

    __shared__ float gwqL[8][50];
    __shared__ float gwT[128][50];

    for (int idx = tid; idx < 8 * 49; idx += 256) {
        int r = idx / 49, c2 = idx - r * 49;
        gwqL[r][c2] = gwb[(qb * 8 + r) * 49 + c2];
    }
    if (tid < 8) gwqL[tid][49] = 0.f;
    __syncthreads();

    // pass A: row max
    float m = -INFINITY;
#pragma unroll
    for (int i = 0; i < 32; ++i) m = fmaxf(m, Srow[l32 + 32 * i]);
#pragma unroll
    for (int off = 16; off; off >>= 1) m = fmaxf(m, __shfl_xor(m, off));

    // pass B: w = e*g written back to S; accumulate Z, SG, T
    float Z = 0.f, SG = 0.f, T = 0.f;
    const float2* gq = (const float2*)&gwqL[ql][0];
    for (int kt = 0; kt < 8; ++kt) {
        __syncthreads();
        for (int idx = tid; idx < 128 * 49; idx += 256) {
            int r = idx / 49, c2 = idx - r * 49;
            gwT[r][c2] = gwb[(kt * 128 + r) * 49 + c2];
        }
        if (tid < 128) gwT[tid][49] = 0.f;
        __syncthreads();
#pragma unroll
        for (int ii = 0; ii < 4; ++ii) {
            const int kl = l32 + 32 * ii;
            const int k  = kt * 128 + kl;
            float e = expf(Srow[k] - m);
            const float2* rowp = (const float2*)&gwT[kl][0];
            float gx = 0.f, gy = 0.f;
#pragma unroll
            for (int j = 0; j < 25; ++j) {
                float2 bv = rowp[j];
                float2 qv = gq[j];
                gx = fmaf(qv.x, bv.x, gx);
                gy = fmaf(qv.y, bv.y, gy);
            }
            float g = gx + gy;
            float w = e * g;
            Z += e; SG += g; T += w;
            Srow[k] = w;
        }
    }
#pragma unroll
    for (int off = 16; off; off >>= 1) {
        Z  += __shfl_xor(Z,  off);
        SG += __shfl_xor(SG, off);
        T  += __shfl_xor(T,  off);
    }
    const float c = 1024.f / (Z * (SG + 1e-8f));
    const float f = c / (c * T + 1e-8f);

    // pass C: final attn as bf16 hi/lo
    unsigned short* ShR = Sh + rowg * 1024;
    unsigned short* SlR = Sl + rowg * 1024;
#pragma unroll
    for (int i = 0; i < 32; ++i) {
        const int k = l32 + 32 * i;
        float v = Srow[k] * f;
        unsigned short h = bf16_rn(v);
        ShR[k] = h;
        SlR[k] = bf16_rn(v - bf16f(h));
    }
}

// ==================== launcher =============================================
extern "C" void kernel_launch(void* const* d_in, const int* in_sizes, int n_in,
                              void* d_out, int out_size, void* d_ws, size_t ws_size,
                              hipStream_t stream)
{
    const float* x      = (const float*)d_in[0];   // [32,1024,768]
    const float* w_qkv  = (const float*)d_in[1];   // [768,2304]
    const float* b_qkv  = (const float*)d_in[2];   // [2304]
    const float* w_proj = (const float*)d_in[3];   // [768,768]
    const float* b_proj = (const float*)d_in[4];   // [768]
    const float* w_gp   = (const float*)d_in[5];   // [768,49]
    float* out = (float*)d_out;

    // ---- CB-adaptive workspace (ws budget unknown; R2 proved >=55.3MB) ----
    auto need = [](int CB) -> size_t {
        size_t u = 0;
        u += 2ull * 2304 * 768;            // WqT h+l
        u += 2ull * 768 * 768;             // WpT h+l
        u += 4ull * CB * 1024 * 768;       // Qh,Ql,Kh,Kl (O aliases Q)
        u += 2ull * CB * 1024 * 768;       // VTh,VTl
        u += 2ull * CB * 1024 * 1024;      // Sh,Sl (also aliased as Xh,Xl)
        size_t bytes = u * 2;
        bytes += 4ull * ((size_t)CB * 1024 * 768      // Vf
                       + (size_t)CB * 1024 * 1024     // SC
                       + (size_t)CB * 1024 * 49);     // gw
        return bytes + 4096;
    };
    int CB = 4;
    if (need(4) > ws_size) CB = (need(2) <= ws_size) ? 2 : 1;
    const int MC = CB * 1024;

    char* cur = (char*)d_ws;
    auto alloc_u = [&](size_t n) {
        unsigned short* p = (unsigned short*)cur;
        cur += ((n * 2 + 15) & ~15ull);
        return p;
    };
    auto alloc_f = [&](size_t n) {
        float* p = (float*)cur;
        cur += ((n * 4 + 15) & ~15ull);
        return p;
    };
    unsigned short* WqTh = alloc_u(2304ull * 768);
    unsigned short* WqTl = alloc_u(2304ull * 768);
    unsigned short* WpTh = alloc_u(768ull * 768);
    unsigned short* WpTl = alloc_u(768ull * 768);
    unsigned short* Qh   = alloc_u((size_t)MC * 768);
    unsigned short* Ql   = alloc_u((size_t)MC * 768);
    unsigned short* Kh   = alloc_u((size_t)MC * 768);
    unsigned short* Kl   = alloc_u((size_t)MC * 768);
    unsigned short* VTh  = alloc_u((size_t)MC * 768);
    unsigned short* VTl  = alloc_u((size_t)MC * 768);
    unsigned short* Sh   = alloc_u((size_t)MC * 1024);
    unsigned short* Sl   = alloc_u((size_t)MC * 1024);
    float* Vf  = alloc_f((size_t)MC * 768);
    float* SC  = alloc_f((size_t)MC * 1024);
    float* gwC = alloc_f((size_t)MC * 49);
    unsigned short* Oh = Qh;   // O aliases Q (Q dead after GEMM S=QK^T)
    unsigned short* Ol = Ql;
    unsigned short* Xh = Sh;   // x split aliases S (S not written until step 5,
    unsigned short* Xl = Sl;   //  Xh/Xl dead after step 1)

    const float scale = 1.0f / sqrtf(768.0f);

    // ---- weight prep (once per launch) ----
    tsplit_k<<<dim3(72, 24, 1), 256, 0, stream>>>(w_qkv, WqTh, WqTl, 2304, 0, 768, 0);
    tsplit_k<<<dim3(24, 24, 1), 256, 0, stream>>>(w_proj, WpTh, WpTl, 768, 0, 768, 0);

    for (int c = 0; c < 32 / CB; ++c) {
        const float* xc   = x   + (size_t)c * MC * 768;
        float*       outc = out + (size_t)c * MC * 768;

        // 0) split x -> hi/lo bf16 (one streaming pass; removes in-K-loop
        //    fp32 split from the qkv GEMM so it takes the gload_lds path)
        {
            const long long n8 = (long long)MC * 768 / 8;
            const int nb = (int)((n8 + 255) / 256);
            split_k<<<dim3(nb), 256, 0, stream>>>(xc, Xh, Xl, n8);
        }

        // 1) qkv GEMM: A = Xh/Xl, B = WqT.
        //    Epilogue writes Qh/Ql, Kh/Kl (bf16 hi/lo) and Vf (fp32).
        mgemm<1, true><<<dim3(18, MC / 128, 1), 256, 0, stream>>>(
            Xh, Xl, WqTh, WqTl, b_qkv,
            Qh, Ql, Kh, Kl, Vf, 768, 768, 0, 0, 0, 0, 1.0f);

        // 2) gw = softmax(V @ w_gp)
        gw_k<<<dim3(MC), 64, 0, stream>>>(Vf, w_gp, gwC);

        // 3) V^T hi/lo per batch (for attn@V's B operand)
        tsplit_k<<<dim3(24, 32, CB), 256, 0, stream>>>(
            Vf, VTh, VTl, 768, 1024ll * 768, 1024, 768ll * 1024);

        // 4) S = Q @ K^T * scale (per batch)
        mgemm<0, false><<<dim3(8, 8, CB), 256, 0, stream>>>(
            Qh, Ql, Kh, Kl, nullptr,
            SC, nullptr, nullptr, nullptr, nullptr,
            768, 768, 1024, 1024ll * 768, 1024ll * 768, 1024ll * 1024, scale);

        // 5) attn = normalize(softmax(S)*G) -> Sh/Sl (bf16 hi/lo)
        mod_k3<<<dim3(128, CB), 256, 0, stream>>>(SC, gwC, Sh, Sl);

        // 6) O = attn @ V (per batch) -> Oh/Ol
        mgemm<2, false><<<dim3(6, 8, CB), 256, 0, stream>>>(
            Sh, Sl, VTh, VTl, nullptr,
            Oh, Ol, nullptr, nullptr, nullptr,
            1024, 1024, 768, 1024ll * 1024, 768ll * 1024, 1024ll * 768, 1.0f);

        // 7) out = O @ w_proj + b_proj
        mgemm<0, true><<<dim3(6, MC / 128, 1), 256, 0, stream>>>(
            Oh, Ol, WpTh, WpTl, b_proj,
            outc, nullptr, nullptr, nullptr, nullptr,
            768, 768, 768, 0, 0, 0, 1.0f);
    }
}

// Round 2
// 2057.067 us; speedup vs baseline: 1.3926x; 1.3926x over previous
//
#include <hip/hip_runtime.h>
#include <math.h>

typedef short  bf16x8 __attribute__((ext_vector_type(8)));
typedef float  f32x4  __attribute__((ext_vector_type(4)));

__device__ __forceinline__ unsigned short bf16_rn(float x) {
    unsigned u = __float_as_uint(x);
    u += 0x7fffu + ((u >> 16) & 1u);
    return (unsigned short)(u >> 16);
}
__device__ __forceinline__ float bf16f(unsigned short h) {
    return __uint_as_float(((unsigned)h) << 16);
}

// async global->LDS, 16B per lane. HW writes LDS at wave-uniform base + lane*16
// (m104/m108); per-lane GLOBAL address carries the layout permutation (m173).
__device__ __forceinline__ void gl2lds16(const void* gptr, void* lptr) {
    __builtin_amdgcn_global_load_lds(
        (const __attribute__((address_space(1))) unsigned int*)(unsigned long long)gptr,
        (__attribute__((address_space(3))) unsigned int*)(unsigned int)(unsigned long long)lptr,
        16, 0, 0);
}

// ==================== MFMA split-bf16 GEMM =================================
// C = scale*(A@B) [+ bias], computed as Ah*Bh + Ah*Bl + Al*Bh on bf16 MFMA
// (dropped Al*Bl term ~2^-16 relative -- fp32-grade accuracy).
// A operand: [M][K] rows (hi/lo bf16). B operand: [N][K] rows (hi/lo bf16).
// Tile 128x128, BK=32, 256 threads = 4 waves in 2x2, each wave 4x4 of
// 16x16x32 MFMA. LDS layout per array: [dbuf 2][blk 8][kg 4][row 16][8 bf16].
// K-loop is the T3 "minimum 2-phase": issue next tile's global_load_lds into
// buf^1 BEFORE computing on buf; ONE barrier (vmcnt drain) per K-step, so the
// ~200-900cy load latency hides under 48 MFMAs + ds_reads (latency-bound fix).
// OUTM: 0 = fp32 C (o1)    1 = qkv epilogue (o1..o5 = Qh,Ql,Kh,Kl,Vfp32)
//       2 = hi/lo bf16 (o1,o2)
template<int OUTM, bool HAS_BIAS>
__global__ __launch_bounds__(256, 2)
void mgemm(const unsigned short* __restrict__ Ah_, const unsigned short* __restrict__ Al_,
           const unsigned short* __restrict__ Bh_, const unsigned short* __restrict__ Bl_,
           const float* __restrict__ bias,
           void* o1, void* o2, void* o3, void* o4, void* o5,
           int K, int lda, int ldc,
           long long sA, long long sB, long long sC, float scale)
{
    const int tid = threadIdx.x;
    const int bm = blockIdx.y * 128;
    const int bn = blockIdx.x * 128;
    const long long z = blockIdx.z;

    const unsigned short* Ahu = Ah_ + z * sA;
    const unsigned short* Alu = Al_ + z * sA;
    const unsigned short* Bhu = Bh_ + z * sB;
    const unsigned short* Blu = Bl_ + z * sB;

    __shared__ unsigned short LA_h[2][4096], LA_l[2][4096];
    __shared__ unsigned short LB_h[2][4096], LB_l[2][4096];

    const int wv = tid >> 6, wr = wv >> 1, wc = wv & 1, lane = tid & 63;
    const int fro = (lane >> 4) * 128 + (lane & 15) * 8;  // frag offset in blk

    // per-lane staging source offsets (hoisted out of K-loop)
    const int srow = lane & 15, skg = lane >> 4;
    const size_t gaA0 = (size_t)(bm + 16 * wv       + srow) * lda + skg * 8;
    const size_t gaA1 = (size_t)(bm + 16 * (wv + 4) + srow) * lda + skg * 8;
    const size_t gaB0 = (size_t)(bn + 16 * wv       + srow) * lda + skg * 8;
    const size_t gaB1 = (size_t)(bn + 16 * (wv + 4) + srow) * lda + skg * 8;
    const int lo0 = wv * 512, lo1 = (wv + 4) * 512;   // wave-uniform LDS bases

    auto stage = [&](int bb, int k0) {
        gl2lds16(&Ahu[gaA0 + k0], &LA_h[bb][lo0]);
        gl2lds16(&Ahu[gaA1 + k0], &LA_h[bb][lo1]);
        gl2lds16(&Alu[gaA0 + k0], &LA_l[bb][lo0]);
        gl2lds16(&Alu[gaA1 + k0], &LA_l[bb][lo1]);
        gl2lds16(&Bhu[gaB0 + k0], &LB_h[bb][lo0]);
        gl2lds16(&Bhu[gaB1 + k0], &LB_h[bb][lo1]);
        gl2lds16(&Blu[gaB0 + k0], &LB_l[bb][lo0]);
        gl2lds16(&Blu[gaB1 + k0], &LB_l[bb][lo1]);
    };

    f32x4 acc[4][4];
#pragma unroll
    for (int i = 0; i < 4; ++i)
#pragma unroll
        for (int j = 0; j < 4; ++j) acc[i][j] = (f32x4){0.f, 0.f, 0.f, 0.f};

    const int nkt = K >> 5;
    stage(0, 0);
    __syncthreads();                              // prologue tile landed
    int cur = 0;
    for (int kt = 0; kt < nkt; ++kt) {
        if (kt + 1 < nkt) stage(cur ^ 1, (kt + 1) << 5);   // async prefetch
        // ---- compute on buf[cur]: 48 MFMA per wave per BK=32 ----
        bf16x8 bhf[4], blf[4];
#pragma unroll
        for (int ni = 0; ni < 4; ++ni) {
            int off = (wc * 4 + ni) * 512 + fro;
            bhf[ni] = *(const bf16x8*)&LB_h[cur][off];
            blf[ni] = *(const bf16x8*)&LB_l[cur][off];
        }
#pragma unroll
        for (int mi = 0; mi < 4; ++mi) {
            int off = (wr * 4 + mi) * 512 + fro;
            bf16x8 ah = *(const bf16x8*)&LA_h[cur][off];
            bf16x8 al = *(const bf16x8*)&LA_l[cur][off];
#pragma unroll
            for (int ni = 0; ni < 4; ++ni) {
                f32x4 a = acc[mi][ni];
                a = __builtin_amdgcn_mfma_f32_16x16x32_bf16(ah, bhf[ni], a, 0, 0, 0);
                a = __builtin_amdgcn_mfma_f32_16x16x32_bf16(ah, blf[ni], a, 0, 0, 0);
                a = __builtin_amdgcn_mfma_f32_16x16x32_bf16(al, bhf[ni], a, 0, 0, 0);
                acc[mi][ni] = a;
            }
        }
        __syncthreads();   // drains vmcnt(0): prefetch visible; frag reads done
        cur ^= 1;
    }

    // ---- epilogue: C/D layout col=lane&15, row=(lane>>4)*4+r ----
#pragma unroll
    for (int mi = 0; mi < 4; ++mi) {
#pragma unroll
        for (int ni = 0; ni < 4; ++ni) {
            const int grow0 = bm + wr * 64 + mi * 16 + ((lane >> 4) << 2);
            const int gcol  = bn + wc * 64 + ni * 16 + (lane & 15);
            float bb = HAS_BIAS ? bias[gcol] : 0.f;
#pragma unroll
            for (int r = 0; r < 4; ++r) {
                float v = acc[mi][ni][r] * scale + bb;
                const size_t grow = (size_t)(grow0 + r);
                if (OUTM == 0) {
                    ((float*)o1 + z * sC)[grow * ldc + gcol] = v;
                } else if (OUTM == 1) {
                    if (gcol < 768) {
                        unsigned short h = bf16_rn(v);
                        ((unsigned short*)o1)[grow * 768 + gcol] = h;
                        ((unsigned short*)o2)[grow * 768 + gcol] = bf16_rn(v - bf16f(h));
                    } else if (gcol < 1536) {
                        int cc = gcol - 768;
                        unsigned short h = bf16_rn(v);
                        ((unsigned short*)o3)[grow * 768 + cc] = h;
                        ((unsigned short*)o4)[grow * 768 + cc] = bf16_rn(v - bf16f(h));
                    } else {
                        ((float*)o5)[grow * 768 + (gcol - 1536)] = v;
                    }
                } else {
                    unsigned short h = bf16_rn(v);
                    ((unsigned short*)o1 + z * sC)[grow * ldc + gcol] = h;
                    ((unsigned short*)o2 + z * sC)[grow * ldc + gcol] = bf16_rn(v - bf16f(h));
                }
            }
        }
    }
}

// ==================== elementwise fp32 -> hi/lo bf16 split =================
__global__ __launch_bounds__(256)
void split_k(const float* __restrict__ src, unsigned short* __restrict__ dh,
             unsigned short* __restrict__ dl, long long n8)
{
    long long i = (long long)blockIdx.x * 256 + threadIdx.x;
    const long long stride = (long long)gridDim.x * 256;
    for (; i < n8; i += stride) {
        const float4* p = (const float4*)(src + i * 8);
        float4 f0 = p[0], f1 = p[1];
        float ff[8] = {f0.x, f0.y, f0.z, f0.w, f1.x, f1.y, f1.z, f1.w};
        bf16x8 hv, lv;
#pragma unroll
        for (int j = 0; j < 8; ++j) {
            unsigned short h = bf16_rn(ff[j]);
            hv[j] = (short)h;
            lv[j] = (short)bf16_rn(ff[j] - bf16f(h));
        }
        *(bf16x8*)(dh + i * 8) = hv;
        *(bf16x8*)(dl + i * 8) = lv;
    }
}

// ==================== transpose + split to hi/lo bf16 ======================
// src fp32 [R][C] (ld ls) -> dh/dl bf16 [C][R] (ld ld_)
__global__ __launch_bounds__(256)
void tsplit_k(const float* __restrict__ src, unsigned short* __restrict__ dh,
              unsigned short* __restrict__ dl, int ls, long long ss,
              int ld_, long long sd)
{
    src += (long long)blockIdx.z * ss;
    dh  += (long long)blockIdx.z * sd;
    dl  += (long long)blockIdx.z * sd;
    __shared__ float t[32][33];
    const int tx = threadIdx.x & 31, ty = threadIdx.x >> 5;
    const int r0 = blockIdx.y * 32, c0 = blockIdx.x * 32;
#pragma unroll
    for (int i = 0; i < 4; ++i)
        t[ty + 8 * i][tx] = src[(size_t)(r0 + ty + 8 * i) * ls + c0 + tx];
    __syncthreads();
#pragma unroll
    for (int i = 0; i < 4; ++i) {
        float v = t[tx][ty + 8 * i];
        unsigned short h = bf16_rn(v);
        size_t o = (size_t)(c0 + ty + 8 * i) * ld_ + r0 + tx;
        dh[o] = h;
        dl[o] = bf16_rn(v - bf16f(h));
    }
}

// ==================== gw = softmax(V @ w_gp), one wave per row =============
__global__ __launch_bounds__(64)
void gw_k(const float* __restrict__ Vf, const float* __restrict__ wgp,
          float* __restrict__ gw)
{
    const long long row = blockIdx.x;
    const int lane = threadIdx.x;
    const float* v = Vf + row * 768;
    float a0 = 0.f, a1 = 0.f, a2 = 0.f, a3 = 0.f;
    if (lane < 49) {
        for (int d = 0; d < 768; d += 4) {
            float4 vv = *(const float4*)&v[d];
            a0 = fmaf(vv.x, wgp[(d + 0) * 49 + lane], a0);
            a1 = fmaf(vv.y, wgp[(d + 1) * 49 + lane], a1);
            a2 = fmaf(vv.z, wgp[(d + 2) * 49 + lane], a2);
            a3 = fmaf(vv.w, wgp[(d + 3) * 49 + lane], a3);
        }
    }
    float logit = (lane < 49) ? ((a0 + a1) + (a2 + a3)) : -INFINITY;
    float m = logit;
    for (int off = 32; off; off >>= 1) m = fmaxf(m, __shfl_xor(m, off));
    float e = (lane < 49) ? expf(logit - m) : 0.f;
    float s = e;
    for (int off = 32; off; off >>= 1) s += __shfl_xor(s, off);
    if (lane < 49) gw[row * 49 + lane] = e / s;
}

// ==================== fused softmax*G modulation, streaming ================
// attn = w*c/(c*T+eps), w = exp(s-m)*(gw_q.gw_k), c = n/(Z*(SG+eps)).
// 8 q rows/block, 32 threads/row; 3 streaming passes over S (L1/L2-hot)
__global__ __launch_bounds__(256)
void mod_k3(float* __restrict__ S, const float* __restrict__ gw,
            unsigned short* __restrict__ Sh, unsigned short* __restrict__ Sl)
{
    const int qb  = blockIdx.x;           // 0..127
    const int b   = blockIdx.y;           // chunk-local batch
    const int tid = threadIdx.x;
    const int ql  = tid >> 5;             // 0..7
    const int l32 = tid & 31;

    const long long rowg = (long long)b * 1024 + (qb * 8 + ql);
    float* Srow = S + rowg * 1024;
    const float* gwb = gw + (long long)b * 1024 * 49;

    __shared__ float gwqL[8][50];
    __shared__ float gwT[128][50];

    for (int idx = tid; idx < 8 * 49; idx += 256) {
        int r = idx / 49, c2 = idx - r * 49;
        gwqL[r][c2] = gwb[(qb * 8 + r) * 49 + c2];
    }
    if (tid < 8) gwqL[tid][49] = 0.f;
    __syncthreads();

    // pass A: row max
    float m = -INFINITY;
#pragma unroll
    for (int i = 0; i < 32; ++i) m = fmaxf(m, Srow[l32 + 32 * i]);
#pragma unroll
    for (int off = 16; off; off >>= 1) m = fmaxf(m, __shfl_xor(m, off));

    // pass B: w = e*g written back to S; accumulate Z, SG, T
    float Z = 0.f, SG = 0.f, T = 0.f;
    const float2* gq = (const float2*)&gwqL[ql][0];
    for (int kt = 0; kt < 8; ++kt) {
        __syncthreads();
        for (int idx = tid; idx < 128 * 49; idx += 256) {
            int r = idx / 49, c2 = idx - r * 49;
            gwT[r][c2] = gwb[(kt * 128 + r) * 49 + c2];
        }
        if (tid < 128) gwT[tid][49] = 0.f;
        __syncthreads();
#pragma unroll
        for (int ii = 0; ii < 4; ++ii) {
            const int kl = l32 + 32 * ii;
            const int k  = kt * 128 + kl;
            float e = expf(Srow[k] - m);
            const float2* rowp = (const float2*)&gwT[kl][0];
            float gx = 0.f, gy = 0.f;
#pragma unroll
            for (int j = 0; j < 25; ++j) {
                float2 bv = rowp[j];
                float2 qv = gq[j];
                gx = fmaf(qv.x, bv.x, gx);
                gy = fmaf(qv.y, bv.y, gy);
            }
            float g = gx + gy;
            float w = e * g;
            Z += e; SG += g; T += w;
            Srow[k] = w;
        }
    }
#pragma unroll
    for (int off = 16; off; off >>= 1) {
        Z  += __shfl_xor(Z,  off);
        SG += __shfl_xor(SG, off);
        T  += __shfl_xor(T,  off);
    }
    const float c = 1024.f / (Z * (SG + 1e-8f));
    const float f = c / (c * T + 1e-8f);

    // pass C: final attn as bf16 hi/lo
    unsigned short* ShR = Sh + rowg * 1024;
    unsigned short* SlR = Sl + rowg * 1024;
#pragma unroll
    for (int i = 0; i < 32; ++i) {
        const int k = l32 + 32 * i;
        float v = Srow[k] * f;
        unsigned short h = bf16_rn(v);
        ShR[k] = h;
        SlR[k] = bf16_rn(v - bf16f(h));
    }
}

// ==================== launcher =============================================
extern "C" void kernel_launch(void* const* d_in, const int* in_sizes, int n_in,
                              void* d_out, int out_size, void* d_ws, size_t ws_size,
                              hipStream_t stream)
{
    const float* x      = (const float*)d_in[0];   // [32,1024,768]
    const float* w_qkv  = (const float*)d_in[1];   // [768,2304]
    const float* b_qkv  = (const float*)d_in[2];   // [2304]
    const float* w_proj = (const float*)d_in[3];   // [768,768]
    const float* b_proj = (const float*)d_in[4];   // [768]
    const float* w_gp   = (const float*)d_in[5];   // [768,49]
    float* out = (float*)d_out;

    // ---- CB-adaptive workspace (bench proved CB=4 fits; try bigger first:
    // bigger CB => bigger z-grids (less tail) and far fewer dispatches) ----
    auto need = [](int CB) -> size_t {
        size_t u = 0;
        u += 2ull * 2304 * 768;            // WqT h+l
        u += 2ull * 768 * 768;             // WpT h+l
        u += 4ull * CB * 1024 * 768;       // Qh,Ql,Kh,Kl (O aliases Q)
        u += 2ull * CB * 1024 * 768;       // VTh,VTl
        u += 2ull * CB * 1024 * 1024;      // Sh,Sl (also aliased as Xh,Xl)
        size_t bytes = u * 2;
        bytes += 4ull * ((size_t)CB * 1024 * 768      // Vf
                       + (size_t)CB * 1024 * 1024     // SC
                       + (size_t)CB * 1024 * 49);     // gw
        return bytes + 4096;
    };
    int CB = 32;
    while (CB > 1 && need(CB) > ws_size) CB >>= 1;
    const int MC = CB * 1024;

    char* cur = (char*)d_ws;
    auto alloc_u = [&](size_t n) {
        unsigned short* p = (unsigned short*)cur;
        cur += ((n * 2 + 15) & ~15ull);
        return p;
    };
    auto alloc_f = [&](size_t n) {
        float* p = (float*)cur;
        cur += ((n * 4 + 15) & ~15ull);
        return p;
    };
    unsigned short* WqTh = alloc_u(2304ull * 768);
    unsigned short* WqTl = alloc_u(2304ull * 768);
    unsigned short* WpTh = alloc_u(768ull * 768);
    unsigned short* WpTl = alloc_u(768ull * 768);
    unsigned short* Qh   = alloc_u((size_t)MC * 768);
    unsigned short* Ql   = alloc_u((size_t)MC * 768);
    unsigned short* Kh   = alloc_u((size_t)MC * 768);
    unsigned short* Kl   = alloc_u((size_t)MC * 768);
    unsigned short* VTh  = alloc_u((size_t)MC * 768);
    unsigned short* VTl  = alloc_u((size_t)MC * 768);
    unsigned short* Sh   = alloc_u((size_t)MC * 1024);
    unsigned short* Sl   = alloc_u((size_t)MC * 1024);
    float* Vf  = alloc_f((size_t)MC * 768);
    float* SC  = alloc_f((size_t)MC * 1024);
    float* gwC = alloc_f((size_t)MC * 49);
    unsigned short* Oh = Qh;   // O aliases Q (Q dead after GEMM S=QK^T)
    unsigned short* Ol = Ql;
    unsigned short* Xh = Sh;   // x split aliases S (S not written until step 5,
    unsigned short* Xl = Sl;   //  Xh/Xl dead after step 1)

    const float scale = 1.0f / sqrtf(768.0f);

    // ---- weight prep (once per launch) ----
    tsplit_k<<<dim3(72, 24, 1), 256, 0, stream>>>(w_qkv, WqTh, WqTl, 2304, 0, 768, 0);
    tsplit_k<<<dim3(24, 24, 1), 256, 0, stream>>>(w_proj, WpTh, WpTl, 768, 0, 768, 0);

    for (int c = 0; c < 32 / CB; ++c) {
        const float* xc   = x   + (size_t)c * MC * 768;
        float*       outc = out + (size_t)c * MC * 768;

        // 0) split x -> hi/lo bf16
        {
            const long long n8 = (long long)MC * 768 / 8;
            int nb = (int)((n8 + 255) / 256);
            if (nb > 4096) nb = 4096;
            split_k<<<dim3(nb), 256, 0, stream>>>(xc, Xh, Xl, n8);
        }

        // 1) qkv GEMM: A = Xh/Xl, B = WqT -> Qh/Ql, Kh/Kl, Vf
        mgemm<1, true><<<dim3(18, MC / 128, 1), 256, 0, stream>>>(
            Xh, Xl, WqTh, WqTl, b_qkv,
            Qh, Ql, Kh, Kl, Vf, 768, 768, 0, 0, 0, 0, 1.0f);

        // 2) gw = softmax(V @ w_gp)
        gw_k<<<dim3(MC), 64, 0, stream>>>(Vf, w_gp, gwC);

        // 3) V^T hi/lo per batch (for attn@V's B operand)
        tsplit_k<<<dim3(24, 32, CB), 256, 0, stream>>>(
            Vf, VTh, VTl, 768, 1024ll * 768, 1024, 768ll * 1024);

        // 4) S = Q @ K^T * scale (per batch)
        mgemm<0, false><<<dim3(8, 8, CB), 256, 0, stream>>>(
            Qh, Ql, Kh, Kl, nullptr,
            SC, nullptr, nullptr, nullptr, nullptr,
            768, 768, 1024, 1024ll * 768, 1024ll * 768, 1024ll * 1024, scale);

        // 5) attn = normalize(softmax(S)*G) -> Sh/Sl (bf16 hi/lo)
        mod_k3<<<dim3(128, CB), 256, 0, stream>>>(SC, gwC, Sh, Sl);

        // 6) O = attn @ V (per batch) -> Oh/Ol
        mgemm<2, false><<<dim3(6, 8, CB), 256, 0, stream>>>(
            Sh, Sl, VTh, VTl, nullptr,
            Oh, Ol, nullptr, nullptr, nullptr,
            1024, 1024, 768, 1024ll * 1024, 768ll * 1024, 1024ll * 768, 1.0f);

        // 7) out = O @ w_proj + b_proj
        mgemm<0, true><<<dim3(6, MC / 128, 1), 256, 0, stream>>>(
            Oh, Ol, WpTh, WpTl, b_proj,
            outc, nullptr, nullptr, nullptr, nullptr,
            768, 768, 768, 0, 0, 0, 1.0f);
    }
}